// Round 11
// baseline (207.128 us; speedup 1.0000x reference)
//
#include <hip/hip_runtime.h>
#include <limits.h>

// Exploits: batch[] is SORTED -> same-graph is an interval test via bnd[17];
// same-interval IMPLIES same batch, so target test = same-interval &&
// pi[s]==pi[d] && pi[s]!=0 (exact; ~800 true edges of 12.8M).
//
// R11: two source-visible inefficiencies in R10's fused kernel:
//  (a) grid 2048 -> 8192 waves over 12500 chunks = 2:1 imbalance (slow half
//      does 2 chunks per phase, fast half 1) -> ~33% idle tail;
//  (b) phase 2 (el baseline) and phase 3 (src/dst correction) as separate
//      loops -> only 4-8 loads in flight per thread.
// Fix: grid ceil(NW/4)=3125 (ONE chunk per wave per phase, perfect balance)
// and a single per-chunk loop issuing all 12 loads (4 el + 4 src + 4 dst,
// 192 B/thread) before compute; baseline computes under vmcnt(8) while
// src/dst return. R9: wave-contiguous layout (every VMEM instr = 64 lanes x
// 16B contiguous). R3: per-block partials (atomic hot line = 68ns*nblocks).
// R5 FAILED: scattered LDS LUT -> bank conflicts (17-entry walk is
// near-broadcast = conflict-free).

typedef int   iv4 __attribute__((ext_vector_type(4)));
typedef float fv4 __attribute__((ext_vector_type(4)));

#define MAX_PART 4096

// focal contribution for one logit x with binary target t (0/1).
// t=1: 0.25 * softplus(-x) * sigmoid(-x)^2 ; t=0: 0.75 * softplus(x) * sigmoid(x)^2
__device__ __forceinline__ float focal_term(float x, int t) {
    float y = t ? -x : x;
    float e = __expf(-fabsf(y));
    float ce = fmaxf(y, 0.f) + __logf(1.f + e);  // softplus(y) == BCE-with-logits
    float inv = __builtin_amdgcn_rcpf(1.f + e);
    float sg = (y >= 0.f) ? inv : e * inv;       // sigmoid(y) == (1 - p_t)
    float w = t ? 0.25f : 0.75f;                 // alpha_t
    return w * ce * sg * sg;                     // gamma = 2
}

__device__ __forceinline__ float acc_term(float x, int t) {
    return ((x > 0.f) == (t != 0)) ? 1.f : 0.f;
}

__device__ __forceinline__ void block_store4(float v0, float v1, float v2,
                                             float v3, float4* part) {
#pragma unroll
    for (int off = 32; off > 0; off >>= 1) {
        v0 += __shfl_down(v0, off, 64);
        v1 += __shfl_down(v1, off, 64);
        v2 += __shfl_down(v2, off, 64);
        v3 += __shfl_down(v3, off, 64);
    }
    __shared__ float s[4][8];
    int wave = threadIdx.x >> 6;
    int lane = threadIdx.x & 63;
    if (lane == 0) { s[0][wave] = v0; s[1][wave] = v1;
                     s[2][wave] = v2; s[3][wave] = v3; }
    __syncthreads();
    if (threadIdx.x == 0) {
        int nw = blockDim.x >> 6;
        float t0 = 0.f, t1 = 0.f, t2 = 0.f, t3 = 0.f;
        for (int w = 0; w < nw; ++w) {
            t0 += s[0][w]; t1 += s[1][w]; t2 += s[2][w]; t3 += s[3][w];
        }
        part[blockIdx.x] = make_float4(t0, t1, t2, t3);
    }
}

// Fused kernel: per block -- (0) bnd[17] via binary search on sorted batch,
// (1) node focal/acc (pi,nl), (2) per-chunk: el baseline + src/dst walk +
// ctz-compacted correction, all 12 loads issued before compute.
// part[b]=(node_ls,node_ac,edge_ls,edge_ac)
__global__ void __launch_bounds__(256, 4)
fused_kernel(const float* __restrict__ nl,
             const int* __restrict__ batch,
             const int* __restrict__ pi,
             int N,
             const float* __restrict__ el,
             const int* __restrict__ src,
             const int* __restrict__ dst,
             int E, float gscale,
             float4* __restrict__ part) {
    // ---- phase 0: bnd[k] = lower_bound(batch, k), k=0..16 (17 lanes,
    // ~18 L2-resident loads each, once per block)
    __shared__ int bnd[17];
    if (threadIdx.x < 17) {
        int k = threadIdx.x;
        int lo = 0, hi = N;
        while (lo < hi) {
            int mid = (lo + hi) >> 1;
            if (batch[mid] < k) lo = mid + 1; else hi = mid;
        }
        bnd[k] = lo;
    }
    __syncthreads();

    int tid = blockIdx.x * blockDim.x + threadIdx.x;
    int nth = gridDim.x * blockDim.x;
    int lane = threadIdx.x & 63;
    int wid = tid >> 6;
    int nwaves = nth >> 6;
    float nls = 0.f, nac = 0.f, els = 0.f, eac = 0.f;

    // ---- phase 1: node pass, 8 nodes/thread (pi + nl only; no batch)
    int C = N >> 3;
    const iv4* pi4 = reinterpret_cast<const iv4*>(pi);
    const fv4* nl4 = reinterpret_cast<const fv4*>(nl);
    for (int c = tid; c < C; c += nth) {
        iv4 p0 = pi4[(c << 1) + 0], p1 = pi4[(c << 1) + 1];
        fv4 x0 = nl4[(c << 1) + 0], x1 = nl4[(c << 1) + 1];
        int pv[8] = {p0.x, p0.y, p0.z, p0.w, p1.x, p1.y, p1.z, p1.w};
        float xv[8] = {x0.x, x0.y, x0.z, x0.w, x1.x, x1.y, x1.z, x1.w};
#pragma unroll
        for (int j = 0; j < 8; ++j) {
            int t = (pv[j] != 0) ? 1 : 0;
            nls += focal_term(xv[j], t);
            nac += acc_term(xv[j], t);
        }
    }
    if (tid == 0) {  // node tail (N % 8)
        for (int i = C << 3; i < N; ++i) {
            int t = (pi[i] != 0) ? 1 : 0;
            float x = nl[i];
            nls += focal_term(x, t);
            nac += acc_term(x, t);
        }
    }

    // ---- phase 2: unified per-chunk loop. Wave w owns edges
    // [w*1024, (w+1)*1024); lane l loads vec4[base4 + j*64 + l] -> every
    // VMEM instr is 64 lanes x 16B = 1KB contiguous. All 12 loads issued
    // before compute: baseline runs under vmcnt(8) while src/dst return.
    int NW = E >> 10;
    const fv4* el4  = reinterpret_cast<const fv4*>(el);
    const iv4* src4 = reinterpret_cast<const iv4*>(src);
    const iv4* dst4 = reinterpret_cast<const iv4*>(dst);
    for (int w = wid; w < NW; w += nwaves) {
        int base4 = w << 8;
        fv4 x0 = __builtin_nontemporal_load(el4 + base4 + (0 << 6) + lane);
        fv4 x1 = __builtin_nontemporal_load(el4 + base4 + (1 << 6) + lane);
        fv4 x2 = __builtin_nontemporal_load(el4 + base4 + (2 << 6) + lane);
        fv4 x3 = __builtin_nontemporal_load(el4 + base4 + (3 << 6) + lane);
        int si[16], di[16];
#pragma unroll
        for (int j = 0; j < 4; ++j) {
            iv4 s = __builtin_nontemporal_load(src4 + base4 + (j << 6) + lane);
            si[j * 4 + 0] = s.x; si[j * 4 + 1] = s.y;
            si[j * 4 + 2] = s.z; si[j * 4 + 3] = s.w;
        }
#pragma unroll
        for (int j = 0; j < 4; ++j) {
            iv4 d = __builtin_nontemporal_load(dst4 + base4 + (j << 6) + lane);
            di[j * 4 + 0] = d.x; di[j * 4 + 1] = d.y;
            di[j * 4 + 2] = d.z; di[j * 4 + 3] = d.w;
        }
        // el baseline (needs only x0..x3 -> runs under vmcnt(8))
        els += focal_term(x0.x, 0) + focal_term(x0.y, 0) +
               focal_term(x0.z, 0) + focal_term(x0.w, 0) +
               focal_term(x1.x, 0) + focal_term(x1.y, 0) +
               focal_term(x1.z, 0) + focal_term(x1.w, 0) +
               focal_term(x2.x, 0) + focal_term(x2.y, 0) +
               focal_term(x2.z, 0) + focal_term(x2.w, 0) +
               focal_term(x3.x, 0) + focal_term(x3.y, 0) +
               focal_term(x3.z, 0) + focal_term(x3.w, 0);
        eac += acc_term(x0.x, 0) + acc_term(x0.y, 0) +
               acc_term(x0.z, 0) + acc_term(x0.w, 0) +
               acc_term(x1.x, 0) + acc_term(x1.y, 0) +
               acc_term(x1.z, 0) + acc_term(x1.w, 0) +
               acc_term(x2.x, 0) + acc_term(x2.y, 0) +
               acc_term(x2.z, 0) + acc_term(x2.w, 0) +
               acc_term(x3.x, 0) + acc_term(x3.y, 0) +
               acc_term(x3.z, 0) + acc_term(x3.w, 0);
        // same-interval mask via walk over LDS bnd[17] (near-broadcast,
        // conflict-free); interpolation first guess, ~0-1 steps typical.
        unsigned int sameM = 0;
#pragma unroll
        for (int i = 0; i < 16; ++i) {
            int s = si[i], d = di[i];
            int gg = (int)((float)s * gscale);
            gg = gg < 0 ? 0 : (gg > 15 ? 15 : gg);
            int lo = bnd[gg], hi = bnd[gg + 1];
            while (s < lo) { --gg; hi = lo; lo = bnd[gg]; }
            while (s >= hi) { ++gg; lo = hi; hi = bnd[gg + 1]; }
            sameM |= (unsigned int)((d >= lo) & (d < hi)) << i;
        }
        // ctz-compacted pi gathers: avg ~1 iteration/thread (1/16 density)
        while (sameM) {
            int i = (int)__builtin_ctz(sameM);
            sameM &= sameM - 1;
            int s = si[i], d = di[i];
            int ps = pi[s];
            int pd = pi[d];
            if ((ps == pd) & (ps != 0)) {  // same-interval => same batch
                int ei = (w << 10) + ((((i >> 2) << 6) + lane) << 2) + (i & 3);
                float x = el[ei];
                els += focal_term(x, 1) - focal_term(x, 0);
                eac += (x > 0.f) ? 1.f : -1.f;  // integer-exact acc delta
            }
        }
    }
    if (tid == 0) {  // edge tail (E % 1024)
        for (int i = NW << 10; i < E; ++i) {
            float x = el[i];
            int s = src[i], d = dst[i];
            int gg = (int)((float)s * gscale);
            gg = gg < 0 ? 0 : (gg > 15 ? 15 : gg);
            int lo = bnd[gg], hi = bnd[gg + 1];
            while (s < lo) { --gg; hi = lo; lo = bnd[gg]; }
            while (s >= hi) { ++gg; lo = hi; hi = bnd[gg + 1]; }
            int t = 0;
            if ((d >= lo) & (d < hi)) {
                int ps = pi[s], pd = pi[d];
                t = (ps == pd) & (ps != 0);
            }
            els += focal_term(x, t);
            eac += acc_term(x, t);
        }
    }

    block_store4(nls, nac, els, eac, part);
}

// ---- fallback path (ws too small): atomics, direct gathers
__global__ void node_atomic_kernel(const float* __restrict__ nl,
                                   const int* __restrict__ pi,
                                   int N, float* __restrict__ acc) {
    int stride = gridDim.x * blockDim.x;
    float ls = 0.f, ac = 0.f;
    for (int i = blockIdx.x * blockDim.x + threadIdx.x; i < N; i += stride) {
        int t = (pi[i] != 0) ? 1 : 0;
        float x = nl[i];
        ls += focal_term(x, t);
        ac += acc_term(x, t);
    }
#pragma unroll
    for (int off = 32; off > 0; off >>= 1) {
        ls += __shfl_down(ls, off, 64);
        ac += __shfl_down(ac, off, 64);
    }
    if ((threadIdx.x & 63) == 0) {
        atomicAdd(acc + 2, ls);
        atomicAdd(acc + 3, ac);
    }
}

__global__ void edge_kernel_direct(const float* __restrict__ el,
                                   const int* __restrict__ src,
                                   const int* __restrict__ dst,
                                   const int* __restrict__ batch,
                                   const int* __restrict__ pi,
                                   int E, float* __restrict__ acc) {
    int stride = gridDim.x * blockDim.x;
    float ls = 0.f, ac = 0.f;
    for (int i = blockIdx.x * blockDim.x + threadIdx.x; i < E; i += stride) {
        int ps = pi[src[i]], pd = pi[dst[i]];
        int t = (ps == pd) & (batch[src[i]] == batch[dst[i]]) & (ps != 0);
        float x = el[i];
        ls += focal_term(x, t);
        ac += acc_term(x, t);
    }
#pragma unroll
    for (int off = 32; off > 0; off >>= 1) {
        ls += __shfl_down(ls, off, 64);
        ac += __shfl_down(ac, off, 64);
    }
    if ((threadIdx.x & 63) == 0) {
        atomicAdd(acc + 0, ls);
        atomicAdd(acc + 1, ac);
    }
}

// Finalize: sums float4 partials (full path) or reads atomic accumulators
// (fallback). Emits the 5 output scalars.
__global__ void finalize_kernel(const float* __restrict__ acc,
                                const float4* __restrict__ p1, int n1,
                                int use_part,
                                float* __restrict__ out, int E, int N) {
    if (use_part) {
        float nls = 0.f, nac = 0.f, els = 0.f, eac = 0.f;
        for (int i = threadIdx.x; i < n1; i += 256) {
            float4 p = p1[i];
            nls += p.x; nac += p.y; els += p.z; eac += p.w;
        }
#pragma unroll
        for (int off = 32; off > 0; off >>= 1) {
            nls += __shfl_down(nls, off, 64);
            nac += __shfl_down(nac, off, 64);
            els += __shfl_down(els, off, 64);
            eac += __shfl_down(eac, off, 64);
        }
        __shared__ float s[4][4];
        int wave = threadIdx.x >> 6;
        int lane = threadIdx.x & 63;
        if (lane == 0) { s[0][wave] = nls; s[1][wave] = nac;
                         s[2][wave] = els; s[3][wave] = eac; }
        __syncthreads();
        if (threadIdx.x == 0) {
            nls = 0.f; nac = 0.f; els = 0.f; eac = 0.f;
            for (int w = 0; w < 4; ++w) {
                nls += s[0][w]; nac += s[1][w];
                els += s[2][w]; eac += s[3][w];
            }
            float invE = 1.f / (float)E;
            float invN = 1.f / (float)N;
            float elm = els * invE, eam = eac * invE;
            float nlm = nls * invN, nam = nac * invN;
            out[0] = elm + nlm;
            out[1] = elm;
            out[2] = nlm;
            out[3] = eam;
            out[4] = nam;
        }
    } else if (threadIdx.x == 0) {
        float invE = 1.f / (float)E;
        float invN = 1.f / (float)N;
        float elm = acc[0] * invE;
        float eam = acc[1] * invE;
        float nlm = acc[2] * invN;
        float nam = acc[3] * invN;
        out[0] = elm + nlm;
        out[1] = elm;
        out[2] = nlm;
        out[3] = eam;
        out[4] = nam;
    }
}

extern "C" void kernel_launch(void* const* d_in, const int* in_sizes, int n_in,
                              void* d_out, int out_size, void* d_ws, size_t ws_size,
                              hipStream_t stream) {
    const float* edge_logits = (const float*)d_in[0];
    const float* node_logits = (const float*)d_in[1];
    const int*   batch       = (const int*)d_in[2];
    const int*   pinst       = (const int*)d_in[3];
    const int*   eidx        = (const int*)d_in[4];
    const int E = in_sizes[0];
    const int N = in_sizes[1];
    const int* src = eidx;
    const int* dst = eidx + E;
    float* out = (float*)d_out;

    // ws layout: acc[4]@0 | float4 part[MAX_PART]@256
    float* acc = (float*)d_ws;
    float4* part = (float4*)((char*)d_ws + 256);
    size_t need_full = 256 + MAX_PART * sizeof(float4);

    const bool full = (ws_size >= need_full);
    const int block = 256;

    if (full) {
        // one chunk per wave per phase: grid = ceil(NW/4), perfectly balanced
        int NW = E >> 10;
        int g = (NW + 3) >> 2;
        int gn = ((N >> 3) + block - 1) / block;  // ensure node coverage
        if (gn > g) g = gn;
        if (g < 1) g = 1;
        if (g > MAX_PART) g = MAX_PART;  // grid-stride covers rest
        float gscale = 16.0f / (float)N;
        fused_kernel<<<g, block, 0, stream>>>(node_logits, batch, pinst, N,
                                              edge_logits, src, dst, E,
                                              gscale, part);
        finalize_kernel<<<1, 256, 0, stream>>>(acc, part, g, 1, out, E, N);
    } else {
        (void)hipMemsetAsync(d_ws, 0, 16, stream);
        int ng = (N + block - 1) / block;
        if (ng > 2048) ng = 2048;
        node_atomic_kernel<<<ng, block, 0, stream>>>(node_logits, pinst, N, acc);
        int eg = (E + block - 1) / block;
        if (eg > 2048) eg = 2048;
        edge_kernel_direct<<<eg, block, 0, stream>>>(edge_logits, src, dst,
                                                     batch, pinst, E, acc);
        finalize_kernel<<<1, 256, 0, stream>>>(acc, nullptr, 0, 0, out, E, N);
    }
}

// Round 12
// 195.154 us; speedup vs baseline: 1.0614x; 1.0614x over previous
//
#include <hip/hip_runtime.h>
#include <limits.h>

// Exploits: batch[] is SORTED -> same-graph is an interval test via bnd[17];
// same-interval IMPLIES same batch, so target test = same-interval &&
// pi[s]==pi[d] && pi[s]!=0 (exact; ~800 true edges of 12.8M).
//
// R12: occupancy probe on the measured-best R10 structure (200.8us). All
// profiles of this family show the latency/occupancy signature (VALUBusy
// <=34%, HBM <=20%, Occ 30-40%) at 4 blocks/CU. launch_bounds(256,6) caps
// VGPR at ~85 (R10 phases keep <=~40 data regs live, phases are SEPARATE
// loops so registers reuse) -> 6 blocks/CU, 24 waves/CU, +50% latency
// hiding. Grid 1536 = 6 x 256 CUs, single resident pass, grid-stride.
// R1 lesson: (256,8) clamped VGPR to 32 -> 66MB scratch spill; (256,6) is
// the safe intermediate. R10: fused node+baseline+correction, separate
// phase loops, binary-search bnd per block. R9: wave-contiguous layout
// (every VMEM instr = 64 lanes x 16B contiguous). R3: per-block partials
// (atomic hot line = 68ns*nblocks serial floor). R5 FAILED: scattered LDS
// LUT -> bank conflicts (17-entry walk is near-broadcast = conflict-free).

typedef int   iv4 __attribute__((ext_vector_type(4)));
typedef float fv4 __attribute__((ext_vector_type(4)));

#define MAX_PART 4096

// focal contribution for one logit x with binary target t (0/1).
// t=1: 0.25 * softplus(-x) * sigmoid(-x)^2 ; t=0: 0.75 * softplus(x) * sigmoid(x)^2
__device__ __forceinline__ float focal_term(float x, int t) {
    float y = t ? -x : x;
    float e = __expf(-fabsf(y));
    float ce = fmaxf(y, 0.f) + __logf(1.f + e);  // softplus(y) == BCE-with-logits
    float inv = __builtin_amdgcn_rcpf(1.f + e);
    float sg = (y >= 0.f) ? inv : e * inv;       // sigmoid(y) == (1 - p_t)
    float w = t ? 0.25f : 0.75f;                 // alpha_t
    return w * ce * sg * sg;                     // gamma = 2
}

__device__ __forceinline__ float acc_term(float x, int t) {
    return ((x > 0.f) == (t != 0)) ? 1.f : 0.f;
}

__device__ __forceinline__ void block_store4(float v0, float v1, float v2,
                                             float v3, float4* part) {
#pragma unroll
    for (int off = 32; off > 0; off >>= 1) {
        v0 += __shfl_down(v0, off, 64);
        v1 += __shfl_down(v1, off, 64);
        v2 += __shfl_down(v2, off, 64);
        v3 += __shfl_down(v3, off, 64);
    }
    __shared__ float s[4][8];
    int wave = threadIdx.x >> 6;
    int lane = threadIdx.x & 63;
    if (lane == 0) { s[0][wave] = v0; s[1][wave] = v1;
                     s[2][wave] = v2; s[3][wave] = v3; }
    __syncthreads();
    if (threadIdx.x == 0) {
        int nw = blockDim.x >> 6;
        float t0 = 0.f, t1 = 0.f, t2 = 0.f, t3 = 0.f;
        for (int w = 0; w < nw; ++w) {
            t0 += s[0][w]; t1 += s[1][w]; t2 += s[2][w]; t3 += s[3][w];
        }
        part[blockIdx.x] = make_float4(t0, t1, t2, t3);
    }
}

// Fused kernel: per block -- (0) bnd[17] via binary search on sorted batch,
// (1) node focal/acc (pi,nl), (2) el focal(x,0) baseline, (3) src/dst
// correction for the rare true edges. part[b]=(node_ls,node_ac,edge_ls,edge_ac)
__global__ void __launch_bounds__(256, 6)
fused_kernel(const float* __restrict__ nl,
             const int* __restrict__ batch,
             const int* __restrict__ pi,
             int N,
             const float* __restrict__ el,
             const int* __restrict__ src,
             const int* __restrict__ dst,
             int E, float gscale,
             float4* __restrict__ part) {
    // ---- phase 0: bnd[k] = lower_bound(batch, k), k=0..16 (17 lanes,
    // ~18 L2-resident loads each, once per block)
    __shared__ int bnd[17];
    if (threadIdx.x < 17) {
        int k = threadIdx.x;
        int lo = 0, hi = N;
        while (lo < hi) {
            int mid = (lo + hi) >> 1;
            if (batch[mid] < k) lo = mid + 1; else hi = mid;
        }
        bnd[k] = lo;
    }
    __syncthreads();

    int tid = blockIdx.x * blockDim.x + threadIdx.x;
    int nth = gridDim.x * blockDim.x;
    int lane = threadIdx.x & 63;
    int wid = tid >> 6;
    int nwaves = nth >> 6;
    float nls = 0.f, nac = 0.f, els = 0.f, eac = 0.f;

    // ---- phase 1: node pass, 8 nodes/thread (pi + nl only; no batch)
    int C = N >> 3;
    const iv4* pi4 = reinterpret_cast<const iv4*>(pi);
    const fv4* nl4 = reinterpret_cast<const fv4*>(nl);
    for (int c = tid; c < C; c += nth) {
        iv4 p0 = pi4[(c << 1) + 0], p1 = pi4[(c << 1) + 1];
        fv4 x0 = nl4[(c << 1) + 0], x1 = nl4[(c << 1) + 1];
        int pv[8] = {p0.x, p0.y, p0.z, p0.w, p1.x, p1.y, p1.z, p1.w};
        float xv[8] = {x0.x, x0.y, x0.z, x0.w, x1.x, x1.y, x1.z, x1.w};
#pragma unroll
        for (int j = 0; j < 8; ++j) {
            int t = (pv[j] != 0) ? 1 : 0;
            nls += focal_term(xv[j], t);
            nac += acc_term(xv[j], t);
        }
    }
    if (tid == 0) {  // node tail (N % 8)
        for (int i = C << 3; i < N; ++i) {
            int t = (pi[i] != 0) ? 1 : 0;
            float x = nl[i];
            nls += focal_term(x, t);
            nac += acc_term(x, t);
        }
    }

    // ---- phase 2: el baseline. Wave w owns edges [w*1024, w*1024+1024);
    // lane l loads fv4[base4 + j*64 + l] -> each instr 64x16B contiguous.
    int NW = E >> 10;
    const fv4* el4 = reinterpret_cast<const fv4*>(el);
    for (int w = wid; w < NW; w += nwaves) {
        int base4 = w << 8;
#pragma unroll
        for (int j = 0; j < 4; ++j) {
            fv4 x = __builtin_nontemporal_load(el4 + base4 + (j << 6) + lane);
            els += focal_term(x.x, 0) + focal_term(x.y, 0) +
                   focal_term(x.z, 0) + focal_term(x.w, 0);
            eac += acc_term(x.x, 0) + acc_term(x.y, 0) +
                   acc_term(x.z, 0) + acc_term(x.w, 0);
        }
    }
    if (tid == 0) {  // el tail (E % 1024)
        for (int i = NW << 10; i < E; ++i) {
            float x = el[i];
            els += focal_term(x, 0);
            eac += acc_term(x, 0);
        }
    }

    // ---- phase 3: correction. Wave-contiguous src/dst loads, walk mask over
    // LDS bnd[17] (near-broadcast), ctz-compacted pi gathers (~1/thread avg),
    // rare (~1/16000) el load + focal delta.
    const iv4* src4 = reinterpret_cast<const iv4*>(src);
    const iv4* dst4 = reinterpret_cast<const iv4*>(dst);
    for (int w = wid; w < NW; w += nwaves) {
        int base4 = w << 8;
        int si[16], di[16];
#pragma unroll
        for (int j = 0; j < 4; ++j) {
            iv4 s = __builtin_nontemporal_load(src4 + base4 + (j << 6) + lane);
            si[j * 4 + 0] = s.x; si[j * 4 + 1] = s.y;
            si[j * 4 + 2] = s.z; si[j * 4 + 3] = s.w;
        }
#pragma unroll
        for (int j = 0; j < 4; ++j) {
            iv4 d = __builtin_nontemporal_load(dst4 + base4 + (j << 6) + lane);
            di[j * 4 + 0] = d.x; di[j * 4 + 1] = d.y;
            di[j * 4 + 2] = d.z; di[j * 4 + 3] = d.w;
        }
        unsigned int sameM = 0;
#pragma unroll
        for (int i = 0; i < 16; ++i) {
            int s = si[i], d = di[i];
            int gg = (int)((float)s * gscale);
            gg = gg < 0 ? 0 : (gg > 15 ? 15 : gg);
            int lo = bnd[gg], hi = bnd[gg + 1];
            while (s < lo) { --gg; hi = lo; lo = bnd[gg]; }
            while (s >= hi) { ++gg; lo = hi; hi = bnd[gg + 1]; }
            sameM |= (unsigned int)((d >= lo) & (d < hi)) << i;
        }
        while (sameM) {
            int i = (int)__builtin_ctz(sameM);
            sameM &= sameM - 1;
            int s = si[i], d = di[i];
            int ps = pi[s];
            int pd = pi[d];
            if ((ps == pd) & (ps != 0)) {  // same-interval => same batch
                int ei = (w << 10) + ((((i >> 2) << 6) + lane) << 2) + (i & 3);
                float x = el[ei];
                els += focal_term(x, 1) - focal_term(x, 0);
                eac += (x > 0.f) ? 1.f : -1.f;  // integer-exact acc delta
            }
        }
    }
    if (tid == 0) {  // corr tail (E % 1024)
        for (int i = NW << 10; i < E; ++i) {
            int s = src[i], d = dst[i];
            int gg = (int)((float)s * gscale);
            gg = gg < 0 ? 0 : (gg > 15 ? 15 : gg);
            int lo = bnd[gg], hi = bnd[gg + 1];
            while (s < lo) { --gg; hi = lo; lo = bnd[gg]; }
            while (s >= hi) { ++gg; lo = hi; hi = bnd[gg + 1]; }
            if ((d >= lo) & (d < hi)) {
                int ps = pi[s], pd = pi[d];
                if ((ps == pd) & (ps != 0)) {
                    float x = el[i];
                    els += focal_term(x, 1) - focal_term(x, 0);
                    eac += (x > 0.f) ? 1.f : -1.f;
                }
            }
        }
    }

    block_store4(nls, nac, els, eac, part);
}

// ---- fallback path (ws too small): atomics, direct gathers
__global__ void node_atomic_kernel(const float* __restrict__ nl,
                                   const int* __restrict__ pi,
                                   int N, float* __restrict__ acc) {
    int stride = gridDim.x * blockDim.x;
    float ls = 0.f, ac = 0.f;
    for (int i = blockIdx.x * blockDim.x + threadIdx.x; i < N; i += stride) {
        int t = (pi[i] != 0) ? 1 : 0;
        float x = nl[i];
        ls += focal_term(x, t);
        ac += acc_term(x, t);
    }
#pragma unroll
    for (int off = 32; off > 0; off >>= 1) {
        ls += __shfl_down(ls, off, 64);
        ac += __shfl_down(ac, off, 64);
    }
    if ((threadIdx.x & 63) == 0) {
        atomicAdd(acc + 2, ls);
        atomicAdd(acc + 3, ac);
    }
}

__global__ void edge_kernel_direct(const float* __restrict__ el,
                                   const int* __restrict__ src,
                                   const int* __restrict__ dst,
                                   const int* __restrict__ batch,
                                   const int* __restrict__ pi,
                                   int E, float* __restrict__ acc) {
    int stride = gridDim.x * blockDim.x;
    float ls = 0.f, ac = 0.f;
    for (int i = blockIdx.x * blockDim.x + threadIdx.x; i < E; i += stride) {
        int ps = pi[src[i]], pd = pi[dst[i]];
        int t = (ps == pd) & (batch[src[i]] == batch[dst[i]]) & (ps != 0);
        float x = el[i];
        ls += focal_term(x, t);
        ac += acc_term(x, t);
    }
#pragma unroll
    for (int off = 32; off > 0; off >>= 1) {
        ls += __shfl_down(ls, off, 64);
        ac += __shfl_down(ac, off, 64);
    }
    if ((threadIdx.x & 63) == 0) {
        atomicAdd(acc + 0, ls);
        atomicAdd(acc + 1, ac);
    }
}

// Finalize: sums float4 partials (full path) or reads atomic accumulators
// (fallback). Emits the 5 output scalars.
__global__ void finalize_kernel(const float* __restrict__ acc,
                                const float4* __restrict__ p1, int n1,
                                int use_part,
                                float* __restrict__ out, int E, int N) {
    if (use_part) {
        float nls = 0.f, nac = 0.f, els = 0.f, eac = 0.f;
        for (int i = threadIdx.x; i < n1; i += 256) {
            float4 p = p1[i];
            nls += p.x; nac += p.y; els += p.z; eac += p.w;
        }
#pragma unroll
        for (int off = 32; off > 0; off >>= 1) {
            nls += __shfl_down(nls, off, 64);
            nac += __shfl_down(nac, off, 64);
            els += __shfl_down(els, off, 64);
            eac += __shfl_down(eac, off, 64);
        }
        __shared__ float s[4][4];
        int wave = threadIdx.x >> 6;
        int lane = threadIdx.x & 63;
        if (lane == 0) { s[0][wave] = nls; s[1][wave] = nac;
                         s[2][wave] = els; s[3][wave] = eac; }
        __syncthreads();
        if (threadIdx.x == 0) {
            nls = 0.f; nac = 0.f; els = 0.f; eac = 0.f;
            for (int w = 0; w < 4; ++w) {
                nls += s[0][w]; nac += s[1][w];
                els += s[2][w]; eac += s[3][w];
            }
            float invE = 1.f / (float)E;
            float invN = 1.f / (float)N;
            float elm = els * invE, eam = eac * invE;
            float nlm = nls * invN, nam = nac * invN;
            out[0] = elm + nlm;
            out[1] = elm;
            out[2] = nlm;
            out[3] = eam;
            out[4] = nam;
        }
    } else if (threadIdx.x == 0) {
        float invE = 1.f / (float)E;
        float invN = 1.f / (float)N;
        float elm = acc[0] * invE;
        float eam = acc[1] * invE;
        float nlm = acc[2] * invN;
        float nam = acc[3] * invN;
        out[0] = elm + nlm;
        out[1] = elm;
        out[2] = nlm;
        out[3] = eam;
        out[4] = nam;
    }
}

extern "C" void kernel_launch(void* const* d_in, const int* in_sizes, int n_in,
                              void* d_out, int out_size, void* d_ws, size_t ws_size,
                              hipStream_t stream) {
    const float* edge_logits = (const float*)d_in[0];
    const float* node_logits = (const float*)d_in[1];
    const int*   batch       = (const int*)d_in[2];
    const int*   pinst       = (const int*)d_in[3];
    const int*   eidx        = (const int*)d_in[4];
    const int E = in_sizes[0];
    const int N = in_sizes[1];
    const int* src = eidx;
    const int* dst = eidx + E;
    float* out = (float*)d_out;

    // ws layout: acc[4]@0 | float4 part[MAX_PART]@256
    float* acc = (float*)d_ws;
    float4* part = (float4*)((char*)d_ws + 256);
    size_t need_full = 256 + MAX_PART * sizeof(float4);

    const bool full = (ws_size >= need_full);
    const int block = 256;

    if (full) {
        // 6 blocks/CU x 256 CUs all resident in one pass; grid-stride covers
        // NW=12500 chunks (~2 per wave per phase)
        int g = 1536;
        if (g > MAX_PART) g = MAX_PART;
        float gscale = 16.0f / (float)N;
        fused_kernel<<<g, block, 0, stream>>>(node_logits, batch, pinst, N,
                                              edge_logits, src, dst, E,
                                              gscale, part);
        finalize_kernel<<<1, 256, 0, stream>>>(acc, part, g, 1, out, E, N);
    } else {
        (void)hipMemsetAsync(d_ws, 0, 16, stream);
        int ng = (N + block - 1) / block;
        if (ng > 2048) ng = 2048;
        node_atomic_kernel<<<ng, block, 0, stream>>>(node_logits, pinst, N, acc);
        int eg = (E + block - 1) / block;
        if (eg > 2048) eg = 2048;
        edge_kernel_direct<<<eg, block, 0, stream>>>(edge_logits, src, dst,
                                                     batch, pinst, E, acc);
        finalize_kernel<<<1, 256, 0, stream>>>(acc, nullptr, 0, 0, out, E, N);
    }
}